// Round 7
// baseline (635.244 us; speedup 1.0000x reference)
//
#include <hip/hip_runtime.h>

#define NEGV -10000.0f
#define BB 1024
#define TT 512
#define KK 64

// ---------------------------------------------------------------------------
// K0: trans = log_softmax(A + inv_mask*NEG, axis=-1).
// ---------------------------------------------------------------------------
__global__ __launch_bounds__(64)
void trans_kernel(const float* __restrict__ A, const int* __restrict__ inv,
                  float* __restrict__ trans)
{
    const int i = blockIdx.x, j = threadIdx.x;
    float x = A[i * KK + j] + (inv[i * KK + j] ? NEGV : 0.0f);
    float m = x;
    #pragma unroll
    for (int o = 32; o > 0; o >>= 1) m = fmaxf(m, __shfl_xor(m, o));
    float e = expf(x - m);
    float s = e;
    #pragma unroll
    for (int o = 32; o > 0; o >>= 1) s += __shfl_xor(s, o);
    trans[i * KK + j] = (x - m) - logf(s);
}

// ---------------------------------------------------------------------------
// K1: fused Viterbi. One wave per sequence; lane = tag j.
// R7: alpha broadcast via 64 v_readlane (VALU-only, zero memory latency on
// the recurrence chain — R5/R6's LDS round-trip ~310 cyc is gone; forward
// loop has NO LDS reads). Unary prefetched in 4-row batches, double-buffered,
// filled 5-8 steps ahead; u materialized early via asm so any conservative
// vmcnt wait overlaps the tree+scan instead of sitting at the chain tail
// (R1-R6 post-mortems: rotating-ring refills produced drain-all vmcnt ->
// ~1200 cyc/step naked latency; fwd measured ~1650 cyc/step, VALU only 390).
// bp bytes in LDS; backward = pure LDS chase (R5-validated, absmax 0).
// ---------------------------------------------------------------------------

// Fill a 4-register batch with unary rows RB..RB+3 (clamped), lane element j.
#define FILL4(BUF_, RB_)                                                       \
  { _Pragma("unroll")                                                          \
    for (int d_ = 0; d_ < 4; ++d_) {                                           \
        int r_ = (RB_) + d_; if (r_ > TT - 1) r_ = TT - 1;                     \
        BUF_[d_] = ur[r_ * KK + lane];                                         \
    } }

// One Viterbi step at time T_ consuming unary value UV_ (compile-time slot).
#define STEP(T_, UV_)                                                          \
  {                                                                            \
    float sv[KK];                                                              \
    _Pragma("unroll")                                                          \
    for (int i = 0; i < KK; ++i) {                                             \
        int rl_ = __builtin_amdgcn_readlane(__float_as_int(alpha), i);         \
        sv[i] = __int_as_float(rl_) + Treg[i];                                 \
    }                                                                          \
    float u_ = (UV_);                                                          \
    asm volatile("" : "+v"(u_));   /* pull the vmcnt wait ahead of tree+scan */\
    /* m = max_i sv[i] — max3 tree (selection op: association-invariant) */    \
    float l0[22];                                                              \
    _Pragma("unroll")                                                          \
    for (int i = 0; i < 21; ++i)                                               \
        l0[i] = fmaxf(fmaxf(sv[3 * i], sv[3 * i + 1]), sv[3 * i + 2]);         \
    l0[21] = sv[63];                                                           \
    float l1[8];                                                               \
    _Pragma("unroll")                                                          \
    for (int i = 0; i < 7; ++i)                                                \
        l1[i] = fmaxf(fmaxf(l0[3 * i], l0[3 * i + 1]), l0[3 * i + 2]);         \
    l1[7] = l0[21];                                                            \
    float l2a = fmaxf(fmaxf(l1[0], l1[1]), l1[2]);                             \
    float l2b = fmaxf(fmaxf(l1[3], l1[4]), l1[5]);                             \
    float m_  = fmaxf(fmaxf(l2a, l2b), fmaxf(l1[6], l1[7]));                   \
    /* alpha update first: frees next step's readlanes to overlap the scan */  \
    if ((T_) <= len) alpha = m_ + u_;                                          \
    /* first-index argmax: m_ is bitwise one of sv; descending cndmask chain   \
       -> smallest i (exact jnp.argmax ties — validated absmax=0 in R5/R6) */  \
    int idx = 63;                                                              \
    _Pragma("unroll")                                                          \
    for (int i = 62; i >= 0; --i) idx = (sv[i] == m_) ? i : idx;               \
    if ((T_) >= 2 && (T_) <= len)                                              \
        sbp[((T_) - 2) * KK + lane] = (unsigned char)idx;                      \
  }

__global__ __launch_bounds__(64, 1)
void viterbi_kernel(const float* __restrict__ unary, const int* __restrict__ lengths,
                    const float* __restrict__ trans, int* __restrict__ out)
{
    const int lane = threadIdx.x;
    const int b = blockIdx.x;

    __shared__ unsigned char sbp[(TT - 1) * KK];   // bp rows t=2..512 -> [(t-2)*64+j]

    float Treg[KK];                                // Treg[i] = trans[i][lane]
    #pragma unroll
    for (int i = 0; i < KK; ++i) Treg[i] = trans[i * KK + lane];

    const int len = lengths[b];                    // 1..512, wave-uniform
    const float* ur = unary + (long)b * (TT * KK);
    int* orow = out + b * TT;

    // double-buffered 4-row unary batches; slot d of a batch = row RB+d,
    // consumed at t = RB+d+1 (u_t = row t-1).
    float ub0[4], ub1[4];
    FILL4(ub0, 0)                                  // rows 0..3  (t = 1..4)
    FILL4(ub1, 4)                                  // rows 4..7  (t = 5..8)

    float alpha = (lane == 1) ? 0.0f : NEGV;       // GO frame

    for (int tb = 1; tb <= len; tb += 8) {
        STEP(tb + 0, ub0[0]) STEP(tb + 1, ub0[1])
        STEP(tb + 2, ub0[2]) STEP(tb + 3, ub0[3])
        FILL4(ub0, tb + 7)                         // rows for t = tb+8..tb+11
        STEP(tb + 4, ub1[0]) STEP(tb + 5, ub1[1])
        STEP(tb + 6, ub1[2]) STEP(tb + 7, ub1[3])
        FILL4(ub1, tb + 11)                        // rows for t = tb+12..tb+15
    }

    // last = first-index argmax of final alpha
    float mm = alpha;
    #pragma unroll
    for (int o = 32; o > 0; o >>= 1) mm = fmaxf(mm, __shfl_xor(mm, o));
    unsigned long long msk = __ballot(alpha == mm);
    int last = __ffsll(msk) - 1;

    // positions >= len-1 carry `last`
    for (int jj = len - 1 + lane; jj < TT; jj += 64) orow[jj] = last;

    __builtin_amdgcn_s_waitcnt(0);                 // settle DS queue before chase

    // backward: pure LDS pointer chase
    int tag = last;
    for (int t = len; t >= 2; --t) {
        int prev = sbp[(t - 2) * KK + tag];        // same-address broadcast read
        if (lane == 0) orow[t - 2] = prev;
        tag = prev;
    }
}

extern "C" void kernel_launch(void* const* d_in, const int* in_sizes, int n_in,
                              void* d_out, int out_size, void* d_ws, size_t ws_size,
                              hipStream_t stream)
{
    const float* unary   = (const float*)d_in[0];
    const int*   lengths = (const int*)d_in[1];
    const int*   inv     = (const int*)d_in[2];
    const float* A       = (const float*)d_in[3];
    int*         out     = (int*)d_out;

    float* trans = (float*)d_ws;                   // 4096 floats = 16 KB

    trans_kernel<<<KK, KK, 0, stream>>>(A, inv, trans);
    viterbi_kernel<<<BB, KK, 0, stream>>>(unary, lengths, trans, out);
}

// Round 8
// 451.896 us; speedup vs baseline: 1.4057x; 1.4057x over previous
//
#include <hip/hip_runtime.h>

#define NEGV -10000.0f
#define BB 1024
#define TT 512
#define KK 64

typedef float vf2 __attribute__((ext_vector_type(2)));

// Raw barrier: own-wave LDS drain + s_barrier. Deliberately NOT __syncthreads()
// — that emits s_waitcnt vmcnt(0) and drains the unary prefetch queue every
// step (m97-style stall; suspected source of R5's ~600 cyc/step gap).
// lgkmcnt(0) makes this wave's ds_write visible before the partner reads.
#define BAR() asm volatile("s_waitcnt lgkmcnt(0)\n\ts_barrier" ::: "memory")

// ---------------------------------------------------------------------------
// K0: trans = log_softmax(A + inv_mask*NEG, axis=-1).
// ---------------------------------------------------------------------------
__global__ __launch_bounds__(64)
void trans_kernel(const float* __restrict__ A, const int* __restrict__ inv,
                  float* __restrict__ trans)
{
    const int i = blockIdx.x, j = threadIdx.x;
    float x = A[i * KK + j] + (inv[i * KK + j] ? NEGV : 0.0f);
    float m = x;
    #pragma unroll
    for (int o = 32; o > 0; o >>= 1) m = fmaxf(m, __shfl_xor(m, o));
    float e = expf(x - m);
    float s = e;
    #pragma unroll
    for (int o = 32; o > 0; o >>= 1) s += __shfl_xor(s, o);
    trans[i * KK + j] = (x - m) - logf(s);
}

// ---------------------------------------------------------------------------
// K1: fused Viterbi. Block = 128 threads = 2 waves per sequence; lane = tag j;
// wave w covers incoming tags i in [32w, 32w+32).
// R8 rationale (R5-R7 post-mortems): wall ~= 4.3 cyc x per-wave instruction
// count (single-wave issue cadence; VALUBusy pinned ~23%, ILP tricks neutral).
// Fix = halve per-wave instructions and run 2 waves/SIMD (2048 waves).
// Per step: each wave does its half (8 ds_read_b128 + 16 pk_add + tree 17 +
// scan 31x2); wave1 publishes (m1, idx1+32) via one ds_write_b64; wave0
// merges (tie -> wave0 half = smaller i, exact jnp.argmax), adds u, writes
// alpha broadcast + bp byte. bp bytes in LDS; backward = wave0 LDS chase
// (R5-validated, absmax 0).
// ---------------------------------------------------------------------------

#define FILL4(BUF_, RB_)                                                       \
  { _Pragma("unroll")                                                          \
    for (int d_ = 0; d_ < 4; ++d_) {                                           \
        int r_ = (RB_) + d_; if (r_ > TT - 1) r_ = TT - 1;                     \
        BUF_[d_] = ur[r_ * KK + lane];                                         \
    } }

#define STEP(T_, UV_)                                                          \
  {                                                                            \
    /* sv[il] = alpha_{t-1}[32w+il] + trans[32w+il][lane] */                   \
    float sv[32];                                                              \
    _Pragma("unroll")                                                          \
    for (int q = 0; q < 8; ++q) {                                              \
        vf2 t01 = vf2{a4[q].x, a4[q].y} + Tr2[2 * q];                          \
        vf2 t23 = vf2{a4[q].z, a4[q].w} + Tr2[2 * q + 1];                      \
        sv[4 * q + 0] = t01.x; sv[4 * q + 1] = t01.y;                          \
        sv[4 * q + 2] = t23.x; sv[4 * q + 3] = t23.y;                          \
    }                                                                          \
    /* half-max tree (selection op: association-invariant) */                  \
    float l0[11];                                                              \
    _Pragma("unroll")                                                          \
    for (int i = 0; i < 10; ++i)                                               \
        l0[i] = fmaxf(fmaxf(sv[3 * i], sv[3 * i + 1]), sv[3 * i + 2]);         \
    l0[10] = fmaxf(sv[30], sv[31]);                                            \
    float l1a = fmaxf(fmaxf(l0[0], l0[1]), l0[2]);                             \
    float l1b = fmaxf(fmaxf(l0[3], l0[4]), l0[5]);                             \
    float l1c = fmaxf(fmaxf(l0[6], l0[7]), l0[8]);                             \
    float l1d = fmaxf(l0[9], l0[10]);                                          \
    float mw  = fmaxf(fmaxf(fmaxf(l1a, l1b), l1c), l1d);                       \
    /* first-index scan within half (inline-const candidates) */               \
    int idx = 31;                                                              \
    _Pragma("unroll")                                                          \
    for (int i = 30; i >= 0; --i) idx = (sv[i] == mw) ? i : idx;               \
    if (wv == 1) {                                                             \
        int2 pk; pk.x = __float_as_int(mw); pk.y = idx + 32;                   \
        sMI[lane] = pk;                                                        \
    }                                                                          \
    BAR(); /* B1: wave1's publish visible */                                   \
    if (wv == 0) {                                                             \
        int2 pk = sMI[lane];                                                   \
        float m1 = __int_as_float(pk.x);                                       \
        float m  = fmaxf(mw, m1);                                              \
        int  bpi = (m1 > mw) ? pk.y : idx;   /* tie -> wave0 (smaller i) */    \
        float u_ = (UV_);                                                      \
        asm volatile("" : "+v"(u_));                                           \
        if ((T_) <= len) alpha = m + u_;                                       \
        sA[lane] = alpha;                                                      \
        if ((T_) >= 2 && (T_) <= len)                                          \
            sbp[((T_) - 2) * KK + lane] = (unsigned char)bpi;                  \
    }                                                                          \
    BAR(); /* B2: alpha broadcast visible */                                   \
    {                                                                          \
        const float4* p = (const float4*)sA + wv * 8;                          \
        _Pragma("unroll")                                                      \
        for (int q = 0; q < 8; ++q) a4[q] = p[q];                              \
    }                                                                          \
  }

__global__ __launch_bounds__(128, 1)
void viterbi_kernel(const float* __restrict__ unary, const int* __restrict__ lengths,
                    const float* __restrict__ trans, int* __restrict__ out)
{
    const int tid  = threadIdx.x;
    const int wv   = tid >> 6;                     // wave id 0/1 (uniform per wave)
    const int lane = tid & 63;                     // tag j
    const int b    = blockIdx.x;

    __shared__ unsigned char sbp[(TT - 1) * KK];   // bp rows t=2..512
    __shared__ float sA[KK];                       // alpha broadcast
    __shared__ int2  sMI[KK];                      // wave1 publish: (m1, idx1+32)

    // Tr2[q] = {trans[32w+2q][lane], trans[32w+2q+1][lane]}
    vf2 Tr2[16];
    #pragma unroll
    for (int q = 0; q < 16; ++q) {
        Tr2[q].x = trans[(wv * 32 + 2 * q)     * KK + lane];
        Tr2[q].y = trans[(wv * 32 + 2 * q + 1) * KK + lane];
    }

    const int len = lengths[b];                    // 1..512, uniform per block
    const float* ur = unary + (long)b * (TT * KK);
    int* orow = out + b * TT;

    // unary prefetch (wave0 only), 4-row double-buffered batches
    float ub0[4], ub1[4];
    if (wv == 0) { FILL4(ub0, 0) FILL4(ub1, 4) }   // rows 0..7 for t=1..8

    float alpha = (lane == 1) ? 0.0f : NEGV;       // GO frame (tracked by wave0)
    if (wv == 0) sA[lane] = alpha;
    BAR();

    float4 a4[8];                                  // this wave's half-broadcast
    {
        const float4* p = (const float4*)sA + wv * 8;
        #pragma unroll
        for (int q = 0; q < 8; ++q) a4[q] = p[q];
    }

    for (int tb = 1; tb <= len; tb += 8) {
        STEP(tb + 0, ub0[0]) STEP(tb + 1, ub0[1])
        STEP(tb + 2, ub0[2]) STEP(tb + 3, ub0[3])
        if (wv == 0) FILL4(ub0, tb + 7)            // rows for t = tb+8..tb+11
        STEP(tb + 4, ub1[0]) STEP(tb + 5, ub1[1])
        STEP(tb + 6, ub1[2]) STEP(tb + 7, ub1[3])
        if (wv == 0) FILL4(ub1, tb + 11)           // rows for t = tb+12..tb+15
    }

    if (wv == 1) return;                           // no barriers after the loop

    // last = first-index argmax of final alpha (wave0 holds full alpha)
    float mm = alpha;
    #pragma unroll
    for (int o = 32; o > 0; o >>= 1) mm = fmaxf(mm, __shfl_xor(mm, o));
    unsigned long long msk = __ballot(alpha == mm);
    int last = __ffsll(msk) - 1;

    for (int jj = len - 1 + lane; jj < TT; jj += 64) orow[jj] = last;

    asm volatile("s_waitcnt lgkmcnt(0)" ::: "memory");   // settle own DS queue

    // backward: pure LDS pointer chase (wave0)
    int tag = last;
    for (int t = len; t >= 2; --t) {
        int prev = sbp[(t - 2) * KK + tag];        // same-address broadcast read
        if (lane == 0) orow[t - 2] = prev;
        tag = prev;
    }
}

extern "C" void kernel_launch(void* const* d_in, const int* in_sizes, int n_in,
                              void* d_out, int out_size, void* d_ws, size_t ws_size,
                              hipStream_t stream)
{
    const float* unary   = (const float*)d_in[0];
    const int*   lengths = (const int*)d_in[1];
    const int*   inv     = (const int*)d_in[2];
    const float* A       = (const float*)d_in[3];
    int*         out     = (int*)d_out;

    float* trans = (float*)d_ws;                   // 4096 floats = 16 KB

    trans_kernel<<<KK, KK, 0, stream>>>(A, inv, trans);
    viterbi_kernel<<<BB, 128, 0, stream>>>(unary, lengths, trans, out);
}